// Round 15
// baseline (443.383 us; speedup 1.0000x reference)
//
#include <hip/hip_runtime.h>

#define N_CELLS 10000
#define N_GENES 4000
#define CELL_F  2000
#define CELL_FX 2112   /* 2048 padded self + 64 raw-neigh columns */
#define GENE_F  50
#define GENE_FP 64
#define HID     256
#define LAT     64
#define NCLUST  20
#define N_EDGES 640000

typedef __attribute__((ext_vector_type(8))) short    bf16x8;
typedef __attribute__((ext_vector_type(8))) unsigned short u16x8;
typedef __attribute__((ext_vector_type(4))) float    f32x4;

__device__ __forceinline__ unsigned short f2bf(float f) {
    unsigned int u = __float_as_uint(f);
    unsigned int r = (u + 0x7FFFu + ((u >> 16) & 1u)) >> 16;
    return (unsigned short)r;
}
__device__ __forceinline__ float bf2f(unsigned short h) {
    return __uint_as_float(((unsigned int)h) << 16);
}

#define GLOAD_LDS16(gp, lp) __builtin_amdgcn_global_load_lds( \
    (const __attribute__((address_space(1))) void*)(gp), \
    (__attribute__((address_space(3))) void*)(lp), 16, 0, 0)

// ================= gather primitives =================
struct AggSide {
    const int *ptr, *nbr; const float *val;
    const unsigned short *src, *pre;
    const float *b1, *b2;
    unsigned short *out;
    int srcRow4, srcOff4, preRow, outLd;
};
struct NsSide {
    const int *ptr, *nbr; const float *val;
    const unsigned short *src;
    unsigned short *out;
    int srcRow4, srcOff4, outLd, outOff;
};

__device__ __forceinline__ float4 gather_quarter(const int* nbr, const float* val,
                                                 const ushort4* src4, int srcRow4, int srcOff4,
                                                 int s, int e, int w, int lane)
{
    int n = e - s;
    int chunk = (n + 3) >> 2;
    int ws = s + w * chunk;
    int we = min(ws + chunk, e);
    float4 acc = {0.0f, 0.0f, 0.0f, 0.0f};
    for (int base = ws; base < we; base += 16) {
        int   nb = 0;
        float vb = 0.0f;
        if (lane < 16 && base + lane < we) {
            nb = nbr[base + lane];
            vb = val[base + lane];
        }
        #pragma unroll
        for (int j = 0; j < 16; ++j) {
            int   jj = __shfl(nb, j);
            float vv = __shfl(vb, j);
            ushort4 a = src4[(size_t)jj * srcRow4 + srcOff4 + lane];
            acc.x += vv * bf2f(a.x);
            acc.y += vv * bf2f(a.y);
            acc.z += vv * bf2f(a.z);
            acc.w += vv * bf2f(a.w);
        }
    }
    return acc;
}

// ================= multi-GEMM (descriptor-dispatched, TM x TN tile) =================
// C(M,N) = A(M,K)@BT(N,K)^T [+bias]. K = padded stride, multiple of 64.
// 4 waves. global_load_lds staging (linear LDS dest) with XOR chunk swizzle
// (involution on both sides).
struct GemmDesc {
    const unsigned short *A, *BT;
    const float *bias;
    float *C;
    unsigned short *Cbf;
    int M, N, K;
    int gx, nwg, blk0;
    const float *bias2;        // RSPLIT: second bias
    unsigned short *Cbf2;      // RSPLIT: dest for cols 256:512
    int ld1, ld2;              // RSPLIT: strides for Cbf / Cbf2
};
struct GemmArgs2 { GemmDesc d[2]; };
struct ScatArgs {
    const int *er, *ec; const float *ev;
    int *cur_c, *cur_g;
    int *ci; float *cv; int *gi; float *gv;
};

template<int TM, int TN, bool BIAS, bool WF32, bool WBF, bool TEPI, bool QTAIL, bool SCAT,
         bool RSPLIT, bool NSH>
__global__ __launch_bounds__(256)
void gemm_multi(GemmArgs2 ga, int gemm0, int qstart,
                const float* __restrict__ zq, const float* __restrict__ cent,
                float* __restrict__ qout, ScatArgs sa, NsSide nsa)
{
    constexpr int SMEM = ((TM + TN) * 128 > 16640) ? (TM + TN) * 128 : 16640;
    __shared__ __align__(16) unsigned char smem[SMEM];
    unsigned short* As = (unsigned short*)smem;
    unsigned short* Bs = As + TM * 64;

    // ---------- scatter head (CSR edge scatter) ----------
    if (SCAT && (int)blockIdx.x < gemm0) {
        int e = blockIdx.x * 256 + threadIdx.x;
        int r = sa.er[e], c = sa.ec[e];
        float v = sa.ev[e];
        int pc = atomicAdd(&sa.cur_c[r], 1);
        sa.ci[pc] = c; sa.cv[pc] = v;
        int pg = atomicAdd(&sa.cur_g[c], 1);
        sa.gi[pg] = r; sa.gv[pg] = v;
        return;
    }

    // ---------- neighsum head (rides this dispatch; e.g. cell-ns under gene GEMM) ----------
    if (NSH && (int)blockIdx.x < gemm0) {
        float (*red)[256] = (float (*)[256])smem;
        int r = blockIdx.x;
        int t = threadIdx.x;
        int w = t >> 6;
        int lane = t & 63;
        int s = nsa.ptr[r], e = nsa.ptr[r + 1];
        float4 acc = gather_quarter(nsa.nbr, nsa.val, (const ushort4*)nsa.src,
                                    nsa.srcRow4, nsa.srcOff4, s, e, w, lane);
        *(float4*)&red[w][lane * 4] = acc;
        __syncthreads();
        float x = red[0][t] + red[1][t] + red[2][t] + red[3][t];
        nsa.out[(size_t)r * nsa.outLd + nsa.outOff + t] = f2bf(x);
        return;
    }

    // ---------- q tail (DEC soft assignment) ----------
    if (QTAIL && (int)blockIdx.x >= qstart) {
        float* cs = (float*)smem;
        int tid = threadIdx.x;
        for (int l = tid; l < NCLUST * LAT; l += 256) cs[l] = cent[l];
        __syncthreads();
        int c = (blockIdx.x - qstart) * 256 + tid;
        if (c >= N_CELLS) return;
        float zr[LAT];
        #pragma unroll
        for (int k = 0; k < LAT; ++k) zr[k] = zq[(size_t)c * LAT + k];
        float num[NCLUST];
        float denom = 0.0f;
        for (int j = 0; j < NCLUST; ++j) {
            float d = 0.0f;
            #pragma unroll
            for (int k = 0; k < LAT; ++k) {
                float t = zr[k] - cs[j * LAT + k];
                d += t * t;
            }
            float n = 1.0f / (1.0f + d);
            num[j] = n;
            denom += n;
        }
        float inv = 1.0f / denom;
        for (int j = 0; j < NCLUST; ++j) qout[(size_t)c * NCLUST + j] = num[j] * inv;
        return;
    }

    // ---------- descriptor pick + XCD-bijective swizzle (m204) ----------
    int b = blockIdx.x;
    int p = (b >= ga.d[1].blk0) ? 1 : 0;
    const GemmDesc d = ga.d[p];
    int lin = b - d.blk0;
    int q8 = d.nwg >> 3, r8 = d.nwg & 7;
    int xcd = lin & 7, idx = lin >> 3;
    int wgid = (xcd < r8 ? xcd * (q8 + 1) : r8 * (q8 + 1) + (xcd - r8) * q8) + idx;
    int by = wgid / d.gx;
    int bx = wgid - by * d.gx;

    const int tid  = threadIdx.x;
    const int lane = tid & 63;
    const int w    = tid >> 6;
    const int cn   = lane & 15;
    const int rj   = lane >> 4;
    const int row0 = by * TM;
    const int col0 = bx * TN;

    constexpr int AI = TM / 32;   // A gload_lds insts per wave
    constexpr int BI = TN / 32;   // B gload_lds insts per wave
    constexpr int MF = TM / 64;   // m-fragments per wave
    constexpr int NF = TN / 16;   // n-fragments

    size_t arow[AI];
    unsigned short* ldsA[AI];
    #pragma unroll
    for (int j = 0; j < AI; ++j) {
        int slot = (w * AI + j) * 64 + lane;
        int rs = slot >> 3, ss = slot & 7, cs = ss ^ (rs & 7);
        arow[j] = (size_t)min(row0 + rs, d.M - 1) * d.K + cs * 8;
        ldsA[j] = As + (w * AI + j) * 512;
    }
    size_t brow[BI];
    unsigned short* ldsB[BI];
    #pragma unroll
    for (int j = 0; j < BI; ++j) {
        int slot = (w * BI + j) * 64 + lane;
        int rs = slot >> 3, ss = slot & 7, cs = ss ^ (rs & 7);
        brow[j] = (size_t)(col0 + rs) * d.K + cs * 8;   // BT rows alloc-padded
        ldsB[j] = Bs + (w * BI + j) * 512;
    }

    int aoff0[MF], aoff1[MF];
    #pragma unroll
    for (int mf = 0; mf < MF; ++mf) {
        int rA = w * (TM / 4) + mf * 16 + cn, swA = rA & 7, abase = rA * 64;
        aoff0[mf] = abase + ((rj)     ^ swA) * 8;
        aoff1[mf] = abase + ((rj + 4) ^ swA) * 8;
    }

    f32x4 acc[MF][NF] = {};

    for (int kt = 0; kt < d.K; kt += 64) {
        #pragma unroll
        for (int j = 0; j < AI; ++j) GLOAD_LDS16(d.A + arow[j] + kt, ldsA[j]);
        #pragma unroll
        for (int j = 0; j < BI; ++j) GLOAD_LDS16(d.BT + brow[j] + kt, ldsB[j]);
        __syncthreads();
        bf16x8 a0[MF], a1[MF];
        #pragma unroll
        for (int mf = 0; mf < MF; ++mf) {
            a0[mf] = *(const bf16x8*)&As[aoff0[mf]];
            a1[mf] = *(const bf16x8*)&As[aoff1[mf]];
        }
        #pragma unroll
        for (int f = 0; f < NF; ++f) {
            int rB = f * 16 + cn, swB = rB & 7, bb = rB * 64;
            bf16x8 b0 = *(const bf16x8*)&Bs[bb + ((rj)     ^ swB) * 8];
            bf16x8 b1 = *(const bf16x8*)&Bs[bb + ((rj + 4) ^ swB) * 8];
            #pragma unroll
            for (int mf = 0; mf < MF; ++mf) {
                acc[mf][f] = __builtin_amdgcn_mfma_f32_16x16x32_bf16(a0[mf], b0, acc[mf][f], 0, 0, 0);
                acc[mf][f] = __builtin_amdgcn_mfma_f32_16x16x32_bf16(a1[mf], b1, acc[mf][f], 0, 0, 0);
            }
        }
        __syncthreads();
    }

    if (TEPI) {
        // ---- LDS-transpose epilogue (TM=TN=64): 256B-contiguous f32 writes ----
        float* Cs = (float*)smem;     // [64][65]
        __syncthreads();
        #pragma unroll
        for (int f = 0; f < 4; ++f)
            #pragma unroll
            for (int j = 0; j < 4; ++j)
                Cs[(w * 16 + rj * 4 + j) * 65 + f * 16 + cn] = acc[0][f][j];
        __syncthreads();
        #pragma unroll
        for (int i = 0; i < 4; ++i) {
            int slot = tid + i * 256;
            int rr = slot >> 4, c4 = (slot & 15) * 4;
            int gr = row0 + rr, gc = col0 + c4;
            if (gr < d.M && gc < d.N) {
                const float* cp = &Cs[rr * 65 + c4];
                float4 bv = BIAS ? *(const float4*)&d.bias[gc] : float4{0, 0, 0, 0};
                float4 v;
                v.x = cp[0] + bv.x; v.y = cp[1] + bv.y;
                v.z = cp[2] + bv.z; v.w = cp[3] + bv.w;
                *(float4*)&d.C[(size_t)gr * d.N + gc] = v;
            }
        }
    } else if (RSPLIT) {
        // ---- split epilogue: cols<256 -> relu(acc+b1+b2) -> Cbf (ld1);
        //      cols>=256 -> raw bf16 -> Cbf2 (ld2) ----
        #pragma unroll
        for (int mf = 0; mf < MF; ++mf) {
            #pragma unroll
            for (int f = 0; f < NF; ++f) {
                int col = col0 + f * 16 + cn;
                if (col >= d.N) continue;
                #pragma unroll
                for (int j = 0; j < 4; ++j) {
                    int r = row0 + w * (TM / 4) + mf * 16 + rj * 4 + j;
                    if (r < d.M) {
                        float val = acc[mf][f][j];
                        if (col < 256) {
                            val += d.bias[col] + d.bias2[col];
                            d.Cbf[(size_t)r * d.ld1 + col] = f2bf(fmaxf(val, 0.0f));
                        } else {
                            d.Cbf2[(size_t)r * d.ld2 + (col - 256)] = f2bf(val);
                        }
                    }
                }
            }
        }
    } else {
        // ---- direct epilogue [m89] ----
        #pragma unroll
        for (int mf = 0; mf < MF; ++mf) {
            #pragma unroll
            for (int f = 0; f < NF; ++f) {
                int col = col0 + f * 16 + cn;
                if (col >= d.N) continue;
                float bv = BIAS ? d.bias[col] : 0.0f;
                #pragma unroll
                for (int j = 0; j < 4; ++j) {
                    int r = row0 + w * (TM / 4) + mf * 16 + rj * 4 + j;
                    if (r < d.M) {
                        float val = acc[mf][f][j] + bv;
                        if (WF32) d.C[(size_t)r * d.N + col] = val;
                        if (WBF)  d.Cbf[(size_t)r * d.N + col] = f2bf(val);
                    }
                }
            }
        }
    }
}

// ================= raw neighbor gather (L0 cell side, 64-dim gene rows) =================
__global__ __launch_bounds__(256)
void rawgather_kernel(const int* __restrict__ ptr, const int* __restrict__ nbr,
                      const float* __restrict__ val,
                      const unsigned short* __restrict__ gx,   // genex_bf 4000x64
                      unsigned short* __restrict__ cellx)      // stride CELL_FX
{
    int w = threadIdx.x >> 6, lane = threadIdx.x & 63;
    int r = blockIdx.x * 4 + w;
    int s = ptr[r], e = ptr[r + 1];
    int g = lane >> 4, sub = lane & 15;
    const ushort4* gx4 = (const ushort4*)gx;      // 16 ushort4 per gene row
    float4 acc = {0.0f, 0.0f, 0.0f, 0.0f};
    for (int base = s; base < e; base += 16) {
        int nb = 0; float vb = 0.0f;
        if (lane < 16 && base + lane < e) { nb = nbr[base + lane]; vb = val[base + lane]; }
        #pragma unroll
        for (int jj = 0; jj < 4; ++jj) {
            int ei = jj * 4 + g;
            int j  = __shfl(nb, ei);
            float v = __shfl(vb, ei);
            ushort4 a = gx4[(size_t)j * 16 + sub];
            acc.x += v * bf2f(a.x);
            acc.y += v * bf2f(a.y);
            acc.z += v * bf2f(a.z);
            acc.w += v * bf2f(a.w);
        }
    }
    acc.x += __shfl_xor(acc.x, 16); acc.x += __shfl_xor(acc.x, 32);
    acc.y += __shfl_xor(acc.y, 16); acc.y += __shfl_xor(acc.y, 32);
    acc.z += __shfl_xor(acc.z, 16); acc.z += __shfl_xor(acc.z, 32);
    acc.w += __shfl_xor(acc.w, 16); acc.w += __shfl_xor(acc.w, 32);
    if (lane < 16) {
        ushort4 o;
        o.x = f2bf(acc.x); o.y = f2bf(acc.y); o.z = f2bf(acc.z); o.w = f2bf(acc.w);
        ((ushort4*)(cellx + (size_t)r * CELL_FX + 2048))[sub] = o;
    }
}

// ================= prep: count + input-cvt + weight packs =================
struct PackDesc {
    const float* W1; const float* W2; const float* W3; unsigned short* BT;
    int Kr, Kp, N1, N2, Np, xb, blk0, kcat;
};
struct PackArgs { PackDesc d[8]; };

#define CNT_BLK   2500
#define CVTC_BLK  10000
#define CVTG_BLK  125
#define PACK_BLK0 (CNT_BLK + CVTC_BLK + CVTG_BLK)

__global__ __launch_bounds__(256)
void prep_kernel(const int* __restrict__ er, const int* __restrict__ ec,
                 int* __restrict__ cnt_c, int* __restrict__ cnt_g,
                 const float* __restrict__ cell_x, unsigned short* __restrict__ cellx_bf,
                 const float* __restrict__ gene_x, unsigned short* __restrict__ genex_bf,
                 PackArgs pa)
{
    __shared__ float tile[32][33];
    int b = blockIdx.x;
    int tid = threadIdx.x;
    if (b < CNT_BLK) {
        int e = b * 256 + tid;
        atomicAdd(&cnt_c[er[e]], 1);
        atomicAdd(&cnt_g[ec[e]], 1);
        return;
    }
    if (b < CNT_BLK + CVTC_BLK) {
        int row = b - CNT_BLK;
        int col = tid * 8;                 // cols 0:2048 (neigh cols from rawgather)
        u16x8 v = {0, 0, 0, 0, 0, 0, 0, 0};
        if (col < CELL_F) {
            const float* src = cell_x + (size_t)row * CELL_F + col;
            float4 f0 = *(const float4*)src;
            float4 f1 = *(const float4*)(src + 4);
            v[0] = f2bf(f0.x); v[1] = f2bf(f0.y); v[2] = f2bf(f0.z); v[3] = f2bf(f0.w);
            v[4] = f2bf(f1.x); v[5] = f2bf(f1.y); v[6] = f2bf(f1.z); v[7] = f2bf(f1.w);
        }
        ((u16x8*)(cellx_bf + (size_t)row * CELL_FX))[tid] = v;
        return;
    }
    if (b < PACK_BLK0) {
        int idx = (b - CNT_BLK - CVTC_BLK) * 256 + tid;
        int row = idx >> 3, c8 = idx & 7;
        int col = c8 * 8;
        u16x8 v = {0, 0, 0, 0, 0, 0, 0, 0};
        #pragma unroll
        for (int j = 0; j < 8; ++j)
            if (col + j < GENE_F) v[j] = f2bf(gene_x[(size_t)row * GENE_F + col + j]);
        ((u16x8*)(genex_bf + (size_t)row * GENE_FP))[c8] = v;
        return;
    }
    int pb = b;
    int p = 0;
    #pragma unroll
    for (int i = 1; i < 8; ++i) if (pb >= pa.d[i].blk0) p = i;
    const PackDesc d = pa.d[p];
    int local = pb - d.blk0;
    int kb = local % d.xb, nb = local / d.xb;
    int k0 = kb * 32, n0 = nb * 32;
    int tx = tid & 31, ty = tid >> 5;
    #pragma unroll
    for (int yy = 0; yy < 4; ++yy) {
        int k = k0 + ty + yy * 8;
        int n = n0 + tx;
        float v = 0.0f;
        if (d.kcat) {
            if (n < d.Np)
                v = (k < 256) ? d.W1[(size_t)k * d.N1 + n]
                              : d.W2[(size_t)(k - 256) * d.N1 + n];
        } else if (k < d.Kr) {
            if (n < d.N1) v = d.W1[(size_t)k * d.N1 + n];
            else if (n < d.N1 + d.N2) v = d.W2[(size_t)k * d.N2 + (n - d.N1)];
        } else if (d.W3 && k >= 2048) {
            int kk = k - 2048;                       // cn_w zone: K rows 2048:2112
            if (kk < GENE_F && n < HID) v = d.W3[(size_t)kk * HID + n];
        }
        tile[ty + yy * 8][tx] = v;
    }
    __syncthreads();
    #pragma unroll
    for (int yy = 0; yy < 4; ++yy) {
        int n = n0 + ty + yy * 8;
        int k = k0 + tx;
        if (n < d.Np)
            d.BT[(size_t)n * d.Kp + k] = f2bf(tile[tx][ty + yy * 8]);
    }
}

// ================= CSR scan =================
__global__ __launch_bounds__(1024)
void scan2_kernel(const int* __restrict__ cnt_c, int* __restrict__ ptr_c, int* __restrict__ cur_c,
                  const int* __restrict__ cnt_g, int* __restrict__ ptr_g, int* __restrict__ cur_g)
{
    const int* cnt = blockIdx.x ? cnt_g : cnt_c;
    int* ptr = blockIdx.x ? ptr_g : ptr_c;
    int* cur = blockIdx.x ? cur_g : cur_c;
    int  n   = blockIdx.x ? N_GENES : N_CELLS;
    __shared__ int part[1024];
    int t = threadIdx.x;
    int chunk = (n + 1023) / 1024;
    int lo = t * chunk, hi = min(lo + chunk, n);
    int s = 0;
    for (int i = lo; i < hi; ++i) s += cnt[i];
    part[t] = s;
    __syncthreads();
    #pragma unroll
    for (int off = 1; off < 1024; off <<= 1) {
        int v = (t >= off) ? part[t - off] : 0;
        __syncthreads();
        part[t] += v;
        __syncthreads();
    }
    if (t == 1023) ptr[n] = part[1023];
    int run = part[t] - s;
    for (int i = lo; i < hi; ++i) { ptr[i] = run; cur[i] = run; run += cnt[i]; }
}

// ---- L0 tail: gene agg (blocks 0..ng-1) + gene-side neighsum (blocks ng..2ng-1) ----
__global__ __launch_bounds__(256)
void l0tail_kernel(AggSide A, NsSide N, int ng)
{
    __shared__ __align__(16) float red[4][256];
    int b = blockIdx.x;
    int t = threadIdx.x;
    int w = t >> 6;
    int lane = t & 63;
    if (b < ng) {
        int r = b;
        int s = A.ptr[r], e = A.ptr[r + 1];
        float4 acc = gather_quarter(A.nbr, A.val, (const ushort4*)A.src,
                                    A.srcRow4, A.srcOff4, s, e, w, lane);
        *(float4*)&red[w][lane * 4] = acc;
        __syncthreads();
        float x = red[0][t] + red[1][t] + red[2][t] + red[3][t]
                + bf2f(A.pre[(size_t)r * A.preRow + t]) + A.b1[t] + A.b2[t];
        A.out[(size_t)r * A.outLd + t] = f2bf(fmaxf(x, 0.0f));
    } else {
        int r = b - ng;
        int s = N.ptr[r], e = N.ptr[r + 1];
        float4 acc = gather_quarter(N.nbr, N.val, (const ushort4*)N.src,
                                    N.srcRow4, N.srcOff4, s, e, w, lane);
        *(float4*)&red[w][lane * 4] = acc;
        __syncthreads();
        float x = red[0][t] + red[1][t] + red[2][t] + red[3][t];
        N.out[(size_t)r * N.outLd + N.outOff + t] = f2bf(x);
    }
}

extern "C" void kernel_launch(void* const* d_in, const int* in_sizes, int n_in,
                              void* d_out, int out_size, void* d_ws, size_t ws_size,
                              hipStream_t stream)
{
    const float* cell_x  = (const float*)d_in[0];
    const float* gene_x  = (const float*)d_in[1];
    const int*   er      = (const int*)d_in[2];
    const int*   ec      = (const int*)d_in[3];
    const float* ev      = (const float*)d_in[4];
    const float* l0_cs_w = (const float*)d_in[5];  const float* l0_cs_b = (const float*)d_in[6];
    const float* l0_cn_w = (const float*)d_in[7];  const float* l0_cn_b = (const float*)d_in[8];
    const float* l0_gs_w = (const float*)d_in[9];  const float* l0_gs_b = (const float*)d_in[10];
    const float* l0_gn_w = (const float*)d_in[11]; const float* l0_gn_b = (const float*)d_in[12];
    const float* l1_cs_w = (const float*)d_in[13]; const float* l1_cs_b = (const float*)d_in[14];
    const float* l1_cn_w = (const float*)d_in[15]; const float* l1_cn_b = (const float*)d_in[16];
    const float* l1_gs_w = (const float*)d_in[17]; const float* l1_gs_b = (const float*)d_in[18];
    const float* l1_gn_w = (const float*)d_in[19]; const float* l1_gn_b = (const float*)d_in[20];
    const float* cl_w = (const float*)d_in[21]; const float* cl_b = (const float*)d_in[22];
    const float* gl_w = (const float*)d_in[23]; const float* gl_b = (const float*)d_in[24];
    const float* cd_w = (const float*)d_in[25]; const float* cd_b = (const float*)d_in[26];
    const float* gd_w = (const float*)d_in[27]; const float* gd_b = (const float*)d_in[28];
    const float* centers = (const float*)d_in[29];

    float* out = (float*)d_out;
    float* z_cells    = out;
    float* z_genes    = out + 640000;
    float* cell_recon = out + 896000;
    float* gene_recon = out + 40896000;
    float* q          = out + 80896000;

    // ---- workspace arena ----
    char* wsp = (char*)d_ws;
    auto alloc = [&](size_t bytes) -> void* {
        void* p = (void*)wsp;
        wsp += (bytes + 255) & ~(size_t)255;
        return p;
    };
    unsigned short* c1x_bf   = (unsigned short*)alloc((size_t)N_CELLS * 512 * 2);  // [c1 | A@g1]
    unsigned short* g1x_bf   = (unsigned short*)alloc((size_t)N_GENES * 512 * 2);  // [g1 | A^T@c1]
    unsigned short* pre_gs_bf  = (unsigned short*)alloc((size_t)N_GENES * 256 * 2);
    unsigned short* pre_cgn_bf = (unsigned short*)alloc((size_t)N_CELLS * 256 * 2);
    unsigned short* c2_bf    = (unsigned short*)alloc((size_t)N_CELLS * 256 * 2);
    unsigned short* g2_bf    = (unsigned short*)alloc((size_t)N_GENES * 256 * 2);
    unsigned short* zc_bf    = (unsigned short*)alloc((size_t)N_CELLS * 64 * 2);
    unsigned short* zg_bf    = (unsigned short*)alloc((size_t)N_GENES * 64 * 2);
    unsigned short* cellx_bf = (unsigned short*)alloc((size_t)N_CELLS * CELL_FX * 2);
    unsigned short* genex_bf = (unsigned short*)alloc((size_t)N_GENES * GENE_FP * 2);
    unsigned short* W0cT = (unsigned short*)alloc((size_t)512 * CELL_FX * 2);
    unsigned short* W0gT = (unsigned short*)alloc((size_t)256 * GENE_FP * 2);
    unsigned short* W1cT = (unsigned short*)alloc((size_t)256 * 512 * 2);
    unsigned short* W1gT = (unsigned short*)alloc((size_t)256 * 512 * 2);
    unsigned short* WzcT = (unsigned short*)alloc((size_t)64 * HID * 2);
    unsigned short* WzgT = (unsigned short*)alloc((size_t)64 * HID * 2);
    unsigned short* WdcT = (unsigned short*)alloc((size_t)4032 * 64 * 2);
    unsigned short* WdgT = (unsigned short*)alloc((size_t)10048 * 64 * 2);
    int* cnt_c = (int*)alloc((size_t)(N_CELLS + N_GENES) * 4);
    int* cnt_g = cnt_c + N_CELLS;
    int* ptr_c = (int*)alloc((size_t)(N_CELLS + 1) * 4);
    int* ptr_g = (int*)alloc((size_t)(N_GENES + 1) * 4);
    int* cur_c = (int*)alloc((size_t)N_CELLS * 4);
    int* cur_g = (int*)alloc((size_t)N_GENES * 4);
    int*   ci = (int*)alloc((size_t)N_EDGES * 4);
    float* cv = (float*)alloc((size_t)N_EDGES * 4);
    int*   gi = (int*)alloc((size_t)N_EDGES * 4);
    float* gv = (float*)alloc((size_t)N_EDGES * 4);

    // ---- D1: zero counters ----
    hipMemsetAsync(cnt_c, 0, (size_t)(N_CELLS + N_GENES) * 4, stream);

    // ---- D2: count + input cvt + weight packs ----
    {
        PackArgs pa;
        auto set = [&](int i, const float* W1, const float* W2, const float* W3,
                       unsigned short* BT, int Kr, int Kp, int N1, int N2, int Np,
                       int kcat, int blk0) -> int {
            int xb = Kp / 32, yb = Np / 32;
            pa.d[i] = {W1, W2, W3, BT, Kr, Kp, N1, N2, Np, xb, blk0, kcat};
            return blk0 + xb * yb;
        };
        int nb = PACK_BLK0;
        nb = set(0, l0_cs_w, l0_gn_w, l0_cn_w, W0cT, CELL_F, CELL_FX, HID, HID, 512, 0, nb);
        nb = set(1, l0_gs_w, nullptr, nullptr, W0gT, GENE_F, GENE_FP, HID, 0, 256, 0, nb);
        nb = set(2, l1_cs_w, l1_cn_w, nullptr, W1cT, 512, 512, HID, 0, 256, 1, nb);
        nb = set(3, l1_gs_w, l1_gn_w, nullptr, W1gT, 512, 512, HID, 0, 256, 1, nb);
        nb = set(4, cl_w, nullptr, nullptr, WzcT, HID, HID, LAT, 0, 64, 0, nb);
        nb = set(5, gl_w, nullptr, nullptr, WzgT, HID, HID, LAT, 0, 64, 0, nb);
        nb = set(6, cd_w, nullptr, nullptr, WdcT, LAT, LAT, N_GENES, 0, 4032, 0, nb);
        nb = set(7, gd_w, nullptr, nullptr, WdgT, LAT, LAT, N_CELLS, 0, 10048, 0, nb);
        prep_kernel<<<nb, 256, 0, stream>>>(er, ec, cnt_c, cnt_g,
                                            cell_x, cellx_bf, gene_x, genex_bf, pa);
    }

    // ---- D3: scan (seeds cur = ptr) ----
    scan2_kernel<<<2, 1024, 0, stream>>>(cnt_c, ptr_c, cur_c, cnt_g, ptr_g, cur_g);

    auto mkdesc = [](const unsigned short* A, const unsigned short* BT, const float* bias,
                     float* C, unsigned short* Cbf, int M, int N, int K, int TMv, int TNv,
                     int blk0) -> GemmDesc {
        int gx = (N + TNv - 1) / TNv, gy = (M + TMv - 1) / TMv;
        return {A, BT, bias, C, Cbf, M, N, K, gx, gx * gy, blk0, nullptr, nullptr, 0, 0};
    };
    ScatArgs sa0 = {er, ec, ev, cur_c, cur_g, ci, cv, gi, gv};
    ScatArgs saN = {};
    NsSide   nsN = {};

    // ---- D4: scatter + gene L0 GEMM (N=256 self-projection only, 128x64) ----
    {
        GemmArgs2 ga;
        ga.d[0] = mkdesc(genex_bf, W0gT, nullptr, nullptr, pre_gs_bf, N_GENES, 256, GENE_FP,
                         128, 64, CNT_BLK);
        ga.d[1] = ga.d[0]; ga.d[1].blk0 = 1 << 30;
        gemm_multi<128, 64, false, false, true, false, false, true, false, false>
            <<<CNT_BLK + ga.d[0].nwg, 256, 0, stream>>>(
            ga, CNT_BLK, 1 << 30, nullptr, nullptr, nullptr, sa0, nsN);
    }

    // ---- D5: raw gene-feature gather into cellx_bf[:, 2048:2112] ----
    rawgather_kernel<<<N_CELLS / 4, 256, 0, stream>>>(ptr_c, ci, cv, genex_bf, cellx_bf);

    // ---- D6: cell L0 GEMM (K=2112; split epilogue -> c1x[:,0:256] + pre_cgn; 128x64) ----
    {
        GemmArgs2 ga;
        ga.d[0] = mkdesc(cellx_bf, W0cT, l0_cs_b, nullptr, c1x_bf, N_CELLS, 512, CELL_FX,
                         128, 64, 0);
        ga.d[0].bias2 = l0_cn_b;
        ga.d[0].Cbf2  = pre_cgn_bf;
        ga.d[0].ld1 = 512; ga.d[0].ld2 = 256;
        ga.d[1] = ga.d[0]; ga.d[1].blk0 = 1 << 30;
        gemm_multi<128, 64, false, false, false, false, false, false, true, false>
            <<<ga.d[0].nwg, 256, 0, stream>>>(
            ga, 0, 1 << 30, nullptr, nullptr, nullptr, saN, nsN);
    }

    // ---- D7: L0 gene agg (gather pre_cgn -> g1x[:,0:256]) ∥ gene neighsum
    //          (gather c1x[:,0:256] -> g1x[:,256:512]) ----
    {
        AggSide A = {ptr_g, gi, gv, pre_cgn_bf, pre_gs_bf, l0_gs_b, l0_gn_b,
                     g1x_bf, 64, 0, 256, 512};
        NsSide  N = {ptr_g, gi, gv, c1x_bf, g1x_bf, 128, 0, 512, 256};
        l0tail_kernel<<<2 * N_GENES, 256, 0, stream>>>(A, N, N_GENES);
    }

    // ---- D8: cell-side neighsum (A@g1 -> c1x[:,256:512]) + gene L1 GEMM
    //          (g1x complete after D7; GEMM reads g1x, ns writes c1x -> no overlap) ----
    {
        NsSide S = {ptr_c, ci, cv, g1x_bf, c1x_bf, 128, 0, 512, 256};
        GemmArgs2 ga;
        ga.d[0] = mkdesc(g1x_bf, W1gT, l1_gs_b, nullptr, g2_bf, N_GENES, 256, 512, 128, 64,
                         N_CELLS);
        ga.d[0].bias2 = l1_gn_b; ga.d[0].ld1 = 256;
        ga.d[1] = ga.d[0]; ga.d[1].blk0 = 1 << 30;
        gemm_multi<128, 64, false, false, false, false, false, false, true, true>
            <<<N_CELLS + ga.d[0].nwg, 256, 0, stream>>>(
            ga, N_CELLS, 1 << 30, nullptr, nullptr, nullptr, saN, S);
    }

    // ---- D9: cell L1 GEMM (K=512, N=256, fused relu+biases -> c2; 128x64) ----
    {
        GemmArgs2 ga;
        ga.d[0] = mkdesc(c1x_bf, W1cT, l1_cs_b, nullptr, c2_bf, N_CELLS, 256, 512, 128, 64, 0);
        ga.d[0].bias2 = l1_cn_b; ga.d[0].ld1 = 256;
        ga.d[1] = ga.d[0]; ga.d[1].blk0 = 1 << 30;
        gemm_multi<128, 64, false, false, false, false, false, false, true, false>
            <<<ga.d[0].nwg, 256, 0, stream>>>(
            ga, 0, 1 << 30, nullptr, nullptr, nullptr, saN, nsN);
    }

    // ---- D10: latent heads (64x64) ----
    {
        GemmArgs2 ga;
        ga.d[0] = mkdesc(c2_bf, WzcT, cl_b, z_cells, zc_bf, N_CELLS, LAT, HID, 64, 64, 0);
        ga.d[1] = mkdesc(g2_bf, WzgT, gl_b, z_genes, zg_bf, N_GENES, LAT, HID, 64, 64,
                         ga.d[0].nwg);
        gemm_multi<64, 64, true, true, true, false, false, false, false, false>
            <<<ga.d[1].blk0 + ga.d[1].nwg, 256, 0, stream>>>(
            ga, 0, 1 << 30, nullptr, nullptr, nullptr, saN, nsN);
    }

    // ---- D11: decoders (64x64, transpose epilogue) + q tail ----
    {
        GemmArgs2 ga;
        ga.d[0] = mkdesc(zc_bf, WdcT, cd_b, cell_recon, nullptr, N_CELLS, N_GENES, LAT,
                         64, 64, 0);
        ga.d[1] = mkdesc(zg_bf, WdgT, gd_b, gene_recon, nullptr, N_GENES, N_CELLS, LAT,
                         64, 64, ga.d[0].nwg);
        int qstart = ga.d[1].blk0 + ga.d[1].nwg;
        int qblocks = (N_CELLS + 255) / 256;
        gemm_multi<64, 64, true, true, false, true, true, false, false, false>
            <<<qstart + qblocks, 256, 0, stream>>>(
            ga, 0, qstart, z_cells, centers, q, saN, nsN);
    }
}

// Round 16
// 419.384 us; speedup vs baseline: 1.0572x; 1.0572x over previous
//
#include <hip/hip_runtime.h>

#define N_CELLS 10000
#define N_GENES 4000
#define CELL_F  2000
#define CELL_FX 2112   /* 2048 padded self + 64 raw-neigh columns */
#define GENE_F  50
#define GENE_FP 64
#define HID     256
#define LAT     64
#define NCLUST  20
#define N_EDGES 640000

typedef __attribute__((ext_vector_type(8))) short    bf16x8;
typedef __attribute__((ext_vector_type(8))) unsigned short u16x8;
typedef __attribute__((ext_vector_type(4))) float    f32x4;

__device__ __forceinline__ unsigned short f2bf(float f) {
    unsigned int u = __float_as_uint(f);
    unsigned int r = (u + 0x7FFFu + ((u >> 16) & 1u)) >> 16;
    return (unsigned short)r;
}
__device__ __forceinline__ float bf2f(unsigned short h) {
    return __uint_as_float(((unsigned int)h) << 16);
}

#define GLOAD_LDS16(gp, lp) __builtin_amdgcn_global_load_lds( \
    (const __attribute__((address_space(1))) void*)(gp), \
    (__attribute__((address_space(3))) void*)(lp), 16, 0, 0)

// ================= multi-GEMM (descriptor-dispatched, 128x64 tile) =================
// C(M,N) = A(M,K)@BT(N,K)^T [+bias]. K = padded stride, multiple of 64.
// 4 waves. global_load_lds staging (linear LDS dest) with XOR chunk swizzle
// (involution on both sides).
struct GemmDesc {
    const unsigned short *A, *BT;
    const float *bias;
    float *C;
    unsigned short *Cbf;
    int M, N, K;
    int gx, nwg, blk0;
    const float *bias2;        // RSPLIT: second bias
    unsigned short *Cbf2;      // RSPLIT: dest for cols 256:512
    int ld1, ld2;              // RSPLIT: strides for Cbf / Cbf2
};
struct GemmArgs2 { GemmDesc d[2]; };
struct ScatArgs {
    const int *er, *ec; const float *ev;
    int *cur_c, *cur_g;
    int *ci; float *cv; int *gi; float *gv;
};

template<int TM, bool BIAS, bool WF32, bool WBF, bool TEPI, bool QTAIL, bool SCAT, bool RSPLIT>
__global__ __launch_bounds__(256)
void gemm_multi(GemmArgs2 ga, int gemm0, int qstart,
                const float* __restrict__ zq, const float* __restrict__ cent,
                float* __restrict__ qout, ScatArgs sa)
{
    constexpr int SMEM = (TM * 128 + 8192) > 16640 ? (TM * 128 + 8192) : 16640;
    __shared__ __align__(16) unsigned char smem[SMEM];
    unsigned short* As = (unsigned short*)smem;
    unsigned short* Bs = As + TM * 64;

    // ---------- scatter head (CSR edge scatter) ----------
    if (SCAT && (int)blockIdx.x < gemm0) {
        int e = blockIdx.x * 256 + threadIdx.x;
        int r = sa.er[e], c = sa.ec[e];
        float v = sa.ev[e];
        int pc = atomicAdd(&sa.cur_c[r], 1);
        sa.ci[pc] = c; sa.cv[pc] = v;
        int pg = atomicAdd(&sa.cur_g[c], 1);
        sa.gi[pg] = r; sa.gv[pg] = v;
        return;
    }

    // ---------- q tail (DEC soft assignment) ----------
    if (QTAIL && (int)blockIdx.x >= qstart) {
        float* cs = (float*)smem;
        int tid = threadIdx.x;
        for (int l = tid; l < NCLUST * LAT; l += 256) cs[l] = cent[l];
        __syncthreads();
        int c = (blockIdx.x - qstart) * 256 + tid;
        if (c >= N_CELLS) return;
        float zr[LAT];
        #pragma unroll
        for (int k = 0; k < LAT; ++k) zr[k] = zq[(size_t)c * LAT + k];
        float num[NCLUST];
        float denom = 0.0f;
        for (int j = 0; j < NCLUST; ++j) {
            float d = 0.0f;
            #pragma unroll
            for (int k = 0; k < LAT; ++k) {
                float t = zr[k] - cs[j * LAT + k];
                d += t * t;
            }
            float n = 1.0f / (1.0f + d);
            num[j] = n;
            denom += n;
        }
        float inv = 1.0f / denom;
        for (int j = 0; j < NCLUST; ++j) qout[(size_t)c * NCLUST + j] = num[j] * inv;
        return;
    }

    // ---------- descriptor pick + XCD-bijective swizzle (m204) ----------
    int b = blockIdx.x;
    int p = (b >= ga.d[1].blk0) ? 1 : 0;
    const GemmDesc d = ga.d[p];
    int lin = b - d.blk0;
    int q8 = d.nwg >> 3, r8 = d.nwg & 7;
    int xcd = lin & 7, idx = lin >> 3;
    int wgid = (xcd < r8 ? xcd * (q8 + 1) : r8 * (q8 + 1) + (xcd - r8) * q8) + idx;
    int by = wgid / d.gx;
    int bx = wgid - by * d.gx;

    const int tid  = threadIdx.x;
    const int lane = tid & 63;
    const int w    = tid >> 6;
    const int cn   = lane & 15;
    const int rj   = lane >> 4;
    const int row0 = by * TM;
    const int col0 = bx * 64;

    constexpr int AI = TM / 32;
    constexpr int MF = TM / 64;

    size_t arow[AI];
    unsigned short* ldsA[AI];
    #pragma unroll
    for (int j = 0; j < AI; ++j) {
        int slot = (w * AI + j) * 64 + lane;
        int rs = slot >> 3, ss = slot & 7, cs = ss ^ (rs & 7);
        arow[j] = (size_t)min(row0 + rs, d.M - 1) * d.K + cs * 8;
        ldsA[j] = As + (w * AI + j) * 512;
    }
    const int sb0 = (w * 2) * 64 + lane;
    const int sb1 = sb0 + 64;
    const int rb0 = sb0 >> 3, cb0 = (sb0 & 7) ^ (rb0 & 7);
    const int rb1 = sb1 >> 3, cb1 = (sb1 & 7) ^ (rb1 & 7);
    const size_t brow0 = (size_t)(col0 + rb0) * d.K + cb0 * 8;
    const size_t brow1 = (size_t)(col0 + rb1) * d.K + cb1 * 8;
    unsigned short* ldsB = Bs + (w * 2) * 512;

    int aoff0[MF], aoff1[MF];
    #pragma unroll
    for (int mf = 0; mf < MF; ++mf) {
        int rA = w * (TM / 4) + mf * 16 + cn, swA = rA & 7, abase = rA * 64;
        aoff0[mf] = abase + ((rj)     ^ swA) * 8;
        aoff1[mf] = abase + ((rj + 4) ^ swA) * 8;
    }

    f32x4 acc[MF][4] = {};

    for (int kt = 0; kt < d.K; kt += 64) {
        #pragma unroll
        for (int j = 0; j < AI; ++j) GLOAD_LDS16(d.A + arow[j] + kt, ldsA[j]);
        GLOAD_LDS16(d.BT + brow0 + kt, ldsB);
        GLOAD_LDS16(d.BT + brow1 + kt, ldsB + 512);
        __syncthreads();
        bf16x8 a0[MF], a1[MF];
        #pragma unroll
        for (int mf = 0; mf < MF; ++mf) {
            a0[mf] = *(const bf16x8*)&As[aoff0[mf]];
            a1[mf] = *(const bf16x8*)&As[aoff1[mf]];
        }
        #pragma unroll
        for (int f = 0; f < 4; ++f) {
            int rB = f * 16 + cn, swB = rB & 7, bb = rB * 64;
            bf16x8 b0 = *(const bf16x8*)&Bs[bb + ((rj)     ^ swB) * 8];
            bf16x8 b1 = *(const bf16x8*)&Bs[bb + ((rj + 4) ^ swB) * 8];
            #pragma unroll
            for (int mf = 0; mf < MF; ++mf) {
                acc[mf][f] = __builtin_amdgcn_mfma_f32_16x16x32_bf16(a0[mf], b0, acc[mf][f], 0, 0, 0);
                acc[mf][f] = __builtin_amdgcn_mfma_f32_16x16x32_bf16(a1[mf], b1, acc[mf][f], 0, 0, 0);
            }
        }
        __syncthreads();
    }

    if (TEPI) {
        // ---- LDS-transpose epilogue (TM=64): 256B-contiguous f32 writes ----
        float* Cs = (float*)smem;     // [64][65]
        __syncthreads();
        #pragma unroll
        for (int f = 0; f < 4; ++f)
            #pragma unroll
            for (int j = 0; j < 4; ++j)
                Cs[(w * 16 + rj * 4 + j) * 65 + f * 16 + cn] = acc[0][f][j];
        __syncthreads();
        #pragma unroll
        for (int i = 0; i < 4; ++i) {
            int slot = tid + i * 256;
            int rr = slot >> 4, c4 = (slot & 15) * 4;
            int gr = row0 + rr, gc = col0 + c4;
            if (gr < d.M && gc < d.N) {
                const float* cp = &Cs[rr * 65 + c4];
                float4 bv = BIAS ? *(const float4*)&d.bias[gc] : float4{0, 0, 0, 0};
                float4 v;
                v.x = cp[0] + bv.x; v.y = cp[1] + bv.y;
                v.z = cp[2] + bv.z; v.w = cp[3] + bv.w;
                *(float4*)&d.C[(size_t)gr * d.N + gc] = v;
            }
        }
    } else if (RSPLIT) {
        // ---- split epilogue: cols<256 -> relu(acc+b1+b2) -> Cbf (ld1);
        //      cols>=256 -> raw bf16 -> Cbf2 (ld2) ----
        #pragma unroll
        for (int mf = 0; mf < MF; ++mf) {
            #pragma unroll
            for (int f = 0; f < 4; ++f) {
                int col = col0 + f * 16 + cn;
                if (col >= d.N) continue;
                #pragma unroll
                for (int j = 0; j < 4; ++j) {
                    int r = row0 + w * (TM / 4) + mf * 16 + rj * 4 + j;
                    if (r < d.M) {
                        float val = acc[mf][f][j];
                        if (col < 256) {
                            val += d.bias[col] + d.bias2[col];
                            d.Cbf[(size_t)r * d.ld1 + col] = f2bf(fmaxf(val, 0.0f));
                        } else {
                            d.Cbf2[(size_t)r * d.ld2 + (col - 256)] = f2bf(val);
                        }
                    }
                }
            }
        }
    } else {
        // ---- direct epilogue [m89] ----
        #pragma unroll
        for (int mf = 0; mf < MF; ++mf) {
            #pragma unroll
            for (int f = 0; f < 4; ++f) {
                int col = col0 + f * 16 + cn;
                if (col >= d.N) continue;
                float bv = BIAS ? d.bias[col] : 0.0f;
                #pragma unroll
                for (int j = 0; j < 4; ++j) {
                    int r = row0 + w * (TM / 4) + mf * 16 + rj * 4 + j;
                    if (r < d.M) {
                        float val = acc[mf][f][j] + bv;
                        if (WF32) d.C[(size_t)r * d.N + col] = val;
                        if (WBF)  d.Cbf[(size_t)r * d.N + col] = f2bf(val);
                    }
                }
            }
        }
    }
}

// ================= raw neighbor gather (L0 cell side, 64-dim gene rows) =================
__global__ __launch_bounds__(256)
void rawgather_kernel(const int* __restrict__ ptr, const int* __restrict__ nbr,
                      const float* __restrict__ val,
                      const unsigned short* __restrict__ gx,   // genex_bf 4000x64
                      unsigned short* __restrict__ cellx)      // stride CELL_FX
{
    int w = threadIdx.x >> 6, lane = threadIdx.x & 63;
    int r = blockIdx.x * 4 + w;
    int s = ptr[r], e = ptr[r + 1];
    int g = lane >> 4, sub = lane & 15;
    const ushort4* gx4 = (const ushort4*)gx;      // 16 ushort4 per gene row
    float4 acc = {0.0f, 0.0f, 0.0f, 0.0f};
    for (int base = s; base < e; base += 16) {
        int nb = 0; float vb = 0.0f;
        if (lane < 16 && base + lane < e) { nb = nbr[base + lane]; vb = val[base + lane]; }
        #pragma unroll
        for (int jj = 0; jj < 4; ++jj) {
            int ei = jj * 4 + g;
            int j  = __shfl(nb, ei);
            float v = __shfl(vb, ei);
            ushort4 a = gx4[(size_t)j * 16 + sub];
            acc.x += v * bf2f(a.x);
            acc.y += v * bf2f(a.y);
            acc.z += v * bf2f(a.z);
            acc.w += v * bf2f(a.w);
        }
    }
    acc.x += __shfl_xor(acc.x, 16); acc.x += __shfl_xor(acc.x, 32);
    acc.y += __shfl_xor(acc.y, 16); acc.y += __shfl_xor(acc.y, 32);
    acc.z += __shfl_xor(acc.z, 16); acc.z += __shfl_xor(acc.z, 32);
    acc.w += __shfl_xor(acc.w, 16); acc.w += __shfl_xor(acc.w, 32);
    if (lane < 16) {
        ushort4 o;
        o.x = f2bf(acc.x); o.y = f2bf(acc.y); o.z = f2bf(acc.z); o.w = f2bf(acc.w);
        ((ushort4*)(cellx + (size_t)r * CELL_FX + 2048))[sub] = o;
    }
}

// ================= prep: count + input-cvt + weight packs =================
struct PackDesc {
    const float* W1; const float* W2; const float* W3; unsigned short* BT;
    int Kr, Kp, N1, N2, Np, xb, blk0, kcat;
};
struct PackArgs { PackDesc d[8]; };

#define CNT_BLK   2500
#define CVTC_BLK  10000
#define CVTG_BLK  125
#define PACK_BLK0 (CNT_BLK + CVTC_BLK + CVTG_BLK)

__global__ __launch_bounds__(256)
void prep_kernel(const int* __restrict__ er, const int* __restrict__ ec,
                 int* __restrict__ cnt_c, int* __restrict__ cnt_g,
                 const float* __restrict__ cell_x, unsigned short* __restrict__ cellx_bf,
                 const float* __restrict__ gene_x, unsigned short* __restrict__ genex_bf,
                 PackArgs pa)
{
    __shared__ float tile[32][33];
    int b = blockIdx.x;
    int tid = threadIdx.x;
    if (b < CNT_BLK) {
        int e = b * 256 + tid;
        atomicAdd(&cnt_c[er[e]], 1);
        atomicAdd(&cnt_g[ec[e]], 1);
        return;
    }
    if (b < CNT_BLK + CVTC_BLK) {
        int row = b - CNT_BLK;
        int col = tid * 8;                 // cols 0:2048 (neigh cols from rawgather)
        u16x8 v = {0, 0, 0, 0, 0, 0, 0, 0};
        if (col < CELL_F) {
            const float* src = cell_x + (size_t)row * CELL_F + col;
            float4 f0 = *(const float4*)src;
            float4 f1 = *(const float4*)(src + 4);
            v[0] = f2bf(f0.x); v[1] = f2bf(f0.y); v[2] = f2bf(f0.z); v[3] = f2bf(f0.w);
            v[4] = f2bf(f1.x); v[5] = f2bf(f1.y); v[6] = f2bf(f1.z); v[7] = f2bf(f1.w);
        }
        ((u16x8*)(cellx_bf + (size_t)row * CELL_FX))[tid] = v;
        return;
    }
    if (b < PACK_BLK0) {
        int idx = (b - CNT_BLK - CVTC_BLK) * 256 + tid;
        int row = idx >> 3, c8 = idx & 7;
        int col = c8 * 8;
        u16x8 v = {0, 0, 0, 0, 0, 0, 0, 0};
        #pragma unroll
        for (int j = 0; j < 8; ++j)
            if (col + j < GENE_F) v[j] = f2bf(gene_x[(size_t)row * GENE_F + col + j]);
        ((u16x8*)(genex_bf + (size_t)row * GENE_FP))[c8] = v;
        return;
    }
    int pb = b;
    int p = 0;
    #pragma unroll
    for (int i = 1; i < 8; ++i) if (pb >= pa.d[i].blk0) p = i;
    const PackDesc d = pa.d[p];
    int local = pb - d.blk0;
    int kb = local % d.xb, nb = local / d.xb;
    int k0 = kb * 32, n0 = nb * 32;
    int tx = tid & 31, ty = tid >> 5;
    #pragma unroll
    for (int yy = 0; yy < 4; ++yy) {
        int k = k0 + ty + yy * 8;
        int n = n0 + tx;
        float v = 0.0f;
        if (d.kcat) {
            // K-concat: rows 0:256 = W1, rows 256:512 = W2 (both KxN1, N=Np)
            if (n < d.Np)
                v = (k < 256) ? d.W1[(size_t)k * d.N1 + n]
                              : d.W2[(size_t)(k - 256) * d.N1 + n];
        } else if (k < d.Kr) {
            if (n < d.N1) v = d.W1[(size_t)k * d.N1 + n];
            else if (n < d.N1 + d.N2) v = d.W2[(size_t)k * d.N2 + (n - d.N1)];
        } else if (d.W3 && k >= 2048) {
            int kk = k - 2048;                       // cn_w zone: K rows 2048:2112
            if (kk < GENE_F && n < HID) v = d.W3[(size_t)kk * HID + n];
        }
        tile[ty + yy * 8][tx] = v;
    }
    __syncthreads();
    #pragma unroll
    for (int yy = 0; yy < 4; ++yy) {
        int n = n0 + ty + yy * 8;
        int k = k0 + tx;
        if (n < d.Np)
            d.BT[(size_t)n * d.Kp + k] = f2bf(tile[tx][ty + yy * 8]);
    }
}

// ================= CSR scan =================
__global__ __launch_bounds__(1024)
void scan2_kernel(const int* __restrict__ cnt_c, int* __restrict__ ptr_c, int* __restrict__ cur_c,
                  const int* __restrict__ cnt_g, int* __restrict__ ptr_g, int* __restrict__ cur_g)
{
    const int* cnt = blockIdx.x ? cnt_g : cnt_c;
    int* ptr = blockIdx.x ? ptr_g : ptr_c;
    int* cur = blockIdx.x ? cur_g : cur_c;
    int  n   = blockIdx.x ? N_GENES : N_CELLS;
    __shared__ int part[1024];
    int t = threadIdx.x;
    int chunk = (n + 1023) / 1024;
    int lo = t * chunk, hi = min(lo + chunk, n);
    int s = 0;
    for (int i = lo; i < hi; ++i) s += cnt[i];
    part[t] = s;
    __syncthreads();
    #pragma unroll
    for (int off = 1; off < 1024; off <<= 1) {
        int v = (t >= off) ? part[t - off] : 0;
        __syncthreads();
        part[t] += v;
        __syncthreads();
    }
    if (t == 1023) ptr[n] = part[1023];
    int run = part[t] - s;   // exclusive prefix for this thread's chunk
    for (int i = lo; i < hi; ++i) { ptr[i] = run; cur[i] = run; run += cnt[i]; }
}

// ================= agg (gene L0): gather + pre + biases + relu =================
struct AggSide {
    const int *ptr, *nbr; const float *val;
    const unsigned short *src, *pre;
    const float *b1, *b2;
    unsigned short *out;
    int srcRow4, srcOff4, preRow, outLd;
};

__global__ __launch_bounds__(256)
void agg1_kernel(AggSide S)
{
    __shared__ __align__(16) float red[4][256];
    int r = blockIdx.x;
    int t = threadIdx.x;
    int w = t >> 6;
    int lane = t & 63;
    int s = S.ptr[r], e = S.ptr[r + 1];
    int n = e - s;
    int chunk = (n + 3) >> 2;
    int ws = s + w * chunk;
    int we = min(ws + chunk, e);
    const ushort4* src4 = (const ushort4*)S.src;
    float4 acc = {0.0f, 0.0f, 0.0f, 0.0f};
    for (int base = ws; base < we; base += 16) {
        int   nb = 0;
        float vb = 0.0f;
        if (lane < 16 && base + lane < we) {
            nb = S.nbr[base + lane];
            vb = S.val[base + lane];
        }
        #pragma unroll
        for (int j = 0; j < 16; ++j) {
            int   jj = __shfl(nb, j);
            float vv = __shfl(vb, j);
            ushort4 a = src4[(size_t)jj * S.srcRow4 + S.srcOff4 + lane];
            acc.x += vv * bf2f(a.x);
            acc.y += vv * bf2f(a.y);
            acc.z += vv * bf2f(a.z);
            acc.w += vv * bf2f(a.w);
        }
    }
    *(float4*)&red[w][lane * 4] = acc;
    __syncthreads();
    float x = red[0][t] + red[1][t] + red[2][t] + red[3][t]
            + bf2f(S.pre[(size_t)r * S.preRow + t]) + S.b1[t] + S.b2[t];
    S.out[(size_t)r * S.outLd + t] = f2bf(fmaxf(x, 0.0f));
}

// ================= neighsum (L1): raw gather -> bf16 K-ext columns =================
struct NsSide {
    const int *ptr, *nbr; const float *val;
    const unsigned short *src;
    unsigned short *out;
    int srcRow4, srcOff4, outLd, outOff;
};
struct NsArgs { NsSide s[2]; int n0; };

__global__ __launch_bounds__(256)
void neighsum_kernel(NsArgs na)
{
    __shared__ __align__(16) float red[4][256];
    int b = blockIdx.x;
    int side = (b >= na.n0) ? 1 : 0;
    const NsSide S = na.s[side];
    int r = side ? b - na.n0 : b;
    int t = threadIdx.x;
    int w = t >> 6;
    int lane = t & 63;
    int s = S.ptr[r], e = S.ptr[r + 1];
    int n = e - s;
    int chunk = (n + 3) >> 2;
    int ws = s + w * chunk;
    int we = min(ws + chunk, e);
    const ushort4* src4 = (const ushort4*)S.src;
    float4 acc = {0.0f, 0.0f, 0.0f, 0.0f};
    for (int base = ws; base < we; base += 16) {
        int   nb = 0;
        float vb = 0.0f;
        if (lane < 16 && base + lane < we) {
            nb = S.nbr[base + lane];
            vb = S.val[base + lane];
        }
        #pragma unroll
        for (int j = 0; j < 16; ++j) {
            int   jj = __shfl(nb, j);
            float vv = __shfl(vb, j);
            ushort4 a = src4[(size_t)jj * S.srcRow4 + S.srcOff4 + lane];
            acc.x += vv * bf2f(a.x);
            acc.y += vv * bf2f(a.y);
            acc.z += vv * bf2f(a.z);
            acc.w += vv * bf2f(a.w);
        }
    }
    *(float4*)&red[w][lane * 4] = acc;
    __syncthreads();
    float x = red[0][t] + red[1][t] + red[2][t] + red[3][t];
    S.out[(size_t)r * S.outLd + S.outOff + t] = f2bf(x);
}

extern "C" void kernel_launch(void* const* d_in, const int* in_sizes, int n_in,
                              void* d_out, int out_size, void* d_ws, size_t ws_size,
                              hipStream_t stream)
{
    const float* cell_x  = (const float*)d_in[0];
    const float* gene_x  = (const float*)d_in[1];
    const int*   er      = (const int*)d_in[2];
    const int*   ec      = (const int*)d_in[3];
    const float* ev      = (const float*)d_in[4];
    const float* l0_cs_w = (const float*)d_in[5];  const float* l0_cs_b = (const float*)d_in[6];
    const float* l0_cn_w = (const float*)d_in[7];  const float* l0_cn_b = (const float*)d_in[8];
    const float* l0_gs_w = (const float*)d_in[9];  const float* l0_gs_b = (const float*)d_in[10];
    const float* l0_gn_w = (const float*)d_in[11]; const float* l0_gn_b = (const float*)d_in[12];
    const float* l1_cs_w = (const float*)d_in[13]; const float* l1_cs_b = (const float*)d_in[14];
    const float* l1_cn_w = (const float*)d_in[15]; const float* l1_cn_b = (const float*)d_in[16];
    const float* l1_gs_w = (const float*)d_in[17]; const float* l1_gs_b = (const float*)d_in[18];
    const float* l1_gn_w = (const float*)d_in[19]; const float* l1_gn_b = (const float*)d_in[20];
    const float* cl_w = (const float*)d_in[21]; const float* cl_b = (const float*)d_in[22];
    const float* gl_w = (const float*)d_in[23]; const float* gl_b = (const float*)d_in[24];
    const float* cd_w = (const float*)d_in[25]; const float* cd_b = (const float*)d_in[26];
    const float* gd_w = (const float*)d_in[27]; const float* gd_b = (const float*)d_in[28];
    const float* centers = (const float*)d_in[29];

    float* out = (float*)d_out;
    float* z_cells    = out;
    float* z_genes    = out + 640000;
    float* cell_recon = out + 896000;
    float* gene_recon = out + 40896000;
    float* q          = out + 80896000;

    // ---- workspace arena ----
    char* wsp = (char*)d_ws;
    auto alloc = [&](size_t bytes) -> void* {
        void* p = (void*)wsp;
        wsp += (bytes + 255) & ~(size_t)255;
        return p;
    };
    unsigned short* c1x_bf   = (unsigned short*)alloc((size_t)N_CELLS * 512 * 2);  // [c1 | A@g1]
    unsigned short* g1x_bf   = (unsigned short*)alloc((size_t)N_GENES * 512 * 2);  // [g1 | A^T@c1]
    unsigned short* pre_gs_bf  = (unsigned short*)alloc((size_t)N_GENES * 256 * 2);
    unsigned short* pre_cgn_bf = (unsigned short*)alloc((size_t)N_CELLS * 256 * 2);
    unsigned short* c2_bf    = (unsigned short*)alloc((size_t)N_CELLS * 256 * 2);
    unsigned short* g2_bf    = (unsigned short*)alloc((size_t)N_GENES * 256 * 2);
    unsigned short* zc_bf    = (unsigned short*)alloc((size_t)N_CELLS * 64 * 2);
    unsigned short* zg_bf    = (unsigned short*)alloc((size_t)N_GENES * 64 * 2);
    unsigned short* cellx_bf = (unsigned short*)alloc((size_t)N_CELLS * CELL_FX * 2);
    unsigned short* genex_bf = (unsigned short*)alloc((size_t)N_GENES * GENE_FP * 2);
    unsigned short* W0cT = (unsigned short*)alloc((size_t)512 * CELL_FX * 2);
    unsigned short* W0gT = (unsigned short*)alloc((size_t)256 * GENE_FP * 2);
    unsigned short* W1cT = (unsigned short*)alloc((size_t)256 * 512 * 2);
    unsigned short* W1gT = (unsigned short*)alloc((size_t)256 * 512 * 2);
    unsigned short* WzcT = (unsigned short*)alloc((size_t)64 * HID * 2);
    unsigned short* WzgT = (unsigned short*)alloc((size_t)64 * HID * 2);
    unsigned short* WdcT = (unsigned short*)alloc((size_t)4032 * 64 * 2);
    unsigned short* WdgT = (unsigned short*)alloc((size_t)10048 * 64 * 2);
    int* cnt_c = (int*)alloc((size_t)(N_CELLS + N_GENES) * 4);
    int* cnt_g = cnt_c + N_CELLS;
    int* ptr_c = (int*)alloc((size_t)(N_CELLS + 1) * 4);
    int* ptr_g = (int*)alloc((size_t)(N_GENES + 1) * 4);
    int* cur_c = (int*)alloc((size_t)N_CELLS * 4);
    int* cur_g = (int*)alloc((size_t)N_GENES * 4);
    int*   ci = (int*)alloc((size_t)N_EDGES * 4);
    float* cv = (float*)alloc((size_t)N_EDGES * 4);
    int*   gi = (int*)alloc((size_t)N_EDGES * 4);
    float* gv = (float*)alloc((size_t)N_EDGES * 4);

    // ---- D1: zero counters ----
    hipMemsetAsync(cnt_c, 0, (size_t)(N_CELLS + N_GENES) * 4, stream);

    // ---- D2: count + input cvt + weight packs ----
    {
        PackArgs pa;
        auto set = [&](int i, const float* W1, const float* W2, const float* W3,
                       unsigned short* BT, int Kr, int Kp, int N1, int N2, int Np,
                       int kcat, int blk0) -> int {
            int xb = Kp / 32, yb = Np / 32;
            pa.d[i] = {W1, W2, W3, BT, Kr, Kp, N1, N2, Np, xb, blk0, kcat};
            return blk0 + xb * yb;
        };
        int nb = PACK_BLK0;
        nb = set(0, l0_cs_w, l0_gn_w, l0_cn_w, W0cT, CELL_F, CELL_FX, HID, HID, 512, 0, nb);
        nb = set(1, l0_gs_w, nullptr, nullptr, W0gT, GENE_F, GENE_FP, HID, 0, 256, 0, nb);
        nb = set(2, l1_cs_w, l1_cn_w, nullptr, W1cT, 512, 512, HID, 0, 256, 1, nb);
        nb = set(3, l1_gs_w, l1_gn_w, nullptr, W1gT, 512, 512, HID, 0, 256, 1, nb);
        nb = set(4, cl_w, nullptr, nullptr, WzcT, HID, HID, LAT, 0, 64, 0, nb);
        nb = set(5, gl_w, nullptr, nullptr, WzgT, HID, HID, LAT, 0, 64, 0, nb);
        nb = set(6, cd_w, nullptr, nullptr, WdcT, LAT, LAT, N_GENES, 0, 4032, 0, nb);
        nb = set(7, gd_w, nullptr, nullptr, WdgT, LAT, LAT, N_CELLS, 0, 10048, 0, nb);
        prep_kernel<<<nb, 256, 0, stream>>>(er, ec, cnt_c, cnt_g,
                                            cell_x, cellx_bf, gene_x, genex_bf, pa);
    }

    // ---- D3: scan (seeds cur = ptr) ----
    scan2_kernel<<<2, 1024, 0, stream>>>(cnt_c, ptr_c, cur_c, cnt_g, ptr_g, cur_g);

    auto mkdesc = [](const unsigned short* A, const unsigned short* BT, const float* bias,
                     float* C, unsigned short* Cbf, int M, int N, int K, int TMv,
                     int blk0) -> GemmDesc {
        int gx = (N + 63) / 64, gy = (M + TMv - 1) / TMv;
        return {A, BT, bias, C, Cbf, M, N, K, gx, gx * gy, blk0, nullptr, nullptr, 0, 0};
    };
    ScatArgs sa0 = {er, ec, ev, cur_c, cur_g, ci, cv, gi, gv};
    ScatArgs saN = {};

    // ---- D4: scatter + gene L0 GEMM (N=256 self-projection only) ----
    {
        GemmArgs2 ga;
        ga.d[0] = mkdesc(genex_bf, W0gT, nullptr, nullptr, pre_gs_bf, N_GENES, 256, GENE_FP, 128, CNT_BLK);
        ga.d[1] = ga.d[0]; ga.d[1].blk0 = 1 << 30;
        gemm_multi<128, false, false, true, false, false, true, false>
            <<<CNT_BLK + ga.d[0].nwg, 256, 0, stream>>>(
            ga, CNT_BLK, 1 << 30, nullptr, nullptr, nullptr, sa0);
    }

    // ---- D5: raw gene-feature gather into cellx_bf[:, 2048:2112] ----
    rawgather_kernel<<<N_CELLS / 4, 256, 0, stream>>>(ptr_c, ci, cv, genex_bf, cellx_bf);

    // ---- D6: cell L0 GEMM (K=2112; split epilogue -> c1x[:,0:256] + pre_cgn) ----
    {
        GemmArgs2 ga;
        ga.d[0] = mkdesc(cellx_bf, W0cT, l0_cs_b, nullptr, c1x_bf, N_CELLS, 512, CELL_FX, 128, 0);
        ga.d[0].bias2 = l0_cn_b;
        ga.d[0].Cbf2  = pre_cgn_bf;
        ga.d[0].ld1 = 512; ga.d[0].ld2 = 256;
        ga.d[1] = ga.d[0]; ga.d[1].blk0 = 1 << 30;
        gemm_multi<128, false, false, false, false, false, false, true>
            <<<ga.d[0].nwg, 256, 0, stream>>>(
            ga, 0, 1 << 30, nullptr, nullptr, nullptr, saN);
    }

    // ---- D7: L0 gene aggregation (gather pre_cgn) -> g1x[:,0:256] ----
    {
        AggSide S = {ptr_g, gi, gv, pre_cgn_bf, pre_gs_bf, l0_gs_b, l0_gn_b,
                     g1x_bf, 64, 0, 256, 512};
        agg1_kernel<<<N_GENES, 256, 0, stream>>>(S);
    }

    // ---- D8: L1 neighbor sums -> K-ext columns (both sides) ----
    {
        NsArgs na;
        na.n0 = N_CELLS;
        na.s[0] = {ptr_c, ci, cv, g1x_bf, c1x_bf, 128, 0, 512, 256};   // A@g1 -> c1x[:,256:512]
        na.s[1] = {ptr_g, gi, gv, c1x_bf, g1x_bf, 128, 0, 512, 256};   // A^T@c1 -> g1x[:,256:512]
        neighsum_kernel<<<N_CELLS + N_GENES, 256, 0, stream>>>(na);
    }

    // ---- D9: L1 GEMMs (K=512, N=256, fused relu+biases -> c2, g2) ----
    {
        GemmArgs2 ga;
        ga.d[0] = mkdesc(c1x_bf, W1cT, l1_cs_b, nullptr, c2_bf, N_CELLS, 256, 512, 128, 0);
        ga.d[0].bias2 = l1_cn_b; ga.d[0].ld1 = 256;
        ga.d[1] = mkdesc(g1x_bf, W1gT, l1_gs_b, nullptr, g2_bf, N_GENES, 256, 512, 128,
                         ga.d[0].nwg);
        ga.d[1].bias2 = l1_gn_b; ga.d[1].ld1 = 256;
        gemm_multi<128, false, false, false, false, false, false, true>
            <<<ga.d[1].blk0 + ga.d[1].nwg, 256, 0, stream>>>(
            ga, 0, 1 << 30, nullptr, nullptr, nullptr, saN);
    }

    // ---- D10: latent heads (TM=64) ----
    {
        GemmArgs2 ga;
        ga.d[0] = mkdesc(c2_bf, WzcT, cl_b, z_cells, zc_bf, N_CELLS, LAT, HID, 64, 0);
        ga.d[1] = mkdesc(g2_bf, WzgT, gl_b, z_genes, zg_bf, N_GENES, LAT, HID, 64, ga.d[0].nwg);
        gemm_multi<64, true, true, true, false, false, false, false>
            <<<ga.d[1].blk0 + ga.d[1].nwg, 256, 0, stream>>>(
            ga, 0, 1 << 30, nullptr, nullptr, nullptr, saN);
    }

    // ---- D11: decoders (TM=64, transpose epilogue) + q tail ----
    {
        GemmArgs2 ga;
        ga.d[0] = mkdesc(zc_bf, WdcT, cd_b, cell_recon, nullptr, N_CELLS, N_GENES, LAT, 64, 0);
        ga.d[1] = mkdesc(zg_bf, WdgT, gd_b, gene_recon, nullptr, N_GENES, N_CELLS, LAT, 64,
                         ga.d[0].nwg);
        int qstart = ga.d[1].blk0 + ga.d[1].nwg;
        int qblocks = (N_CELLS + 255) / 256;
        gemm_multi<64, true, true, false, true, true, false, false>
            <<<qstart + qblocks, 256, 0, stream>>>(
            ga, 0, qstart, z_cells, centers, q, saN);
    }
}